// Round 6
// baseline (561.242 us; speedup 1.0000x reference)
//
#include <hip/hip_runtime.h>

// Problem constants
#define NMAT 50
#define BATCH 128
#define FDIM 1024
#define HDIM 4096
#define ROWS 6400            // BATCH*NMAT
#define PSIZE 320000         // BATCH*NMAT*NMAT
#define NPART 8              // split-K partials for gemm2
#define HINF 1e18

// ws layout (bytes):
//   Mpart : [0, 20480000)           fp64 [8][6400][50] split-K partials
//   Xh/Xl : packed split-bf16 X     [50 mt][32 k0b][4 kg][128 m][8] each 13.1 MB
//   W1h/l : packed split-bf16 W1^T  [32 nt][32 k0b][4 kg][128 n][8] each 8.4 MB
//   W2p   : fp32 [4096][64] zero-padded W2 (1 MB, L2-resident in gemm2)
//   hbuf  : fp32 hT [4096][max_rows] (TRANSPOSED h), chunked to fit ws
#define WS_M_OFF   0
#define WS_XH_OFF  20480000LL
#define WS_XL_OFF  33587200LL
#define WS_W1H_OFF 46694400LL
#define WS_W1L_OFF 55083008LL
#define WS_W2P_OFF 63471616LL
#define WS_H_OFF   64520192LL
#define WS_MIN     (WS_H_OFF + 128LL * HDIM * 4)   // ~66.6 MB

typedef __bf16 bf16x8 __attribute__((ext_vector_type(8)));
typedef float f32x4 __attribute__((ext_vector_type(4)));
typedef double f64x4 __attribute__((ext_vector_type(4)));
typedef unsigned short u16;

__device__ __forceinline__ float bf16_to_f32(unsigned short h) {
  return __uint_as_float(((unsigned int)h) << 16);
}
__device__ __forceinline__ unsigned short f32_to_bf16(float f) {
  unsigned int u = __float_as_uint(f);
  u += 0x7FFFu + ((u >> 16) & 1u);   // RNE
  return (unsigned short)(u >> 16);
}

// async global->LDS, 16B per lane; LDS dest = wave-uniform base + lane*16
__device__ __forceinline__ void gload16(const u16* g, u16* l) {
  __builtin_amdgcn_global_load_lds(
      (const __attribute__((address_space(1))) unsigned int*)g,
      (__attribute__((address_space(3))) unsigned int*)l, 16, 0, 0);
}

// ---- wave-wide fp64 min via DPP (VALU pipe). row_shr:1/2/4/8 within 16-lane
// rows, row_bcast15/31 combine; lane 63 holds the 64-lane min. DPP only
// permutes genuine lane values -> result is SOME lane's cand -> ballot
// non-empty. Round-5 verified.
__device__ __forceinline__ double wave_min_f64(double x) {
  union { double d; int i[2]; } u, t;
  u.d = x;
#define DPP_MIN_STEP(ctrl)                                                   \
  t.i[0] = __builtin_amdgcn_update_dpp(u.i[0], u.i[0], ctrl, 0xf, 0xf, false);\
  t.i[1] = __builtin_amdgcn_update_dpp(u.i[1], u.i[1], ctrl, 0xf, 0xf, false);\
  u.d = fmin(u.d, t.d);
  DPP_MIN_STEP(0x111)  // row_shr:1
  DPP_MIN_STEP(0x112)  // row_shr:2
  DPP_MIN_STEP(0x114)  // row_shr:4
  DPP_MIN_STEP(0x118)  // row_shr:8
  DPP_MIN_STEP(0x142)  // row_bcast15
  DPP_MIN_STEP(0x143)  // row_bcast31
#undef DPP_MIN_STEP
  union { double d; int i[2]; } r;
  r.i[0] = __builtin_amdgcn_readlane(u.i[0], 63);
  r.i[1] = __builtin_amdgcn_readlane(u.i[1], 63);
  return r.d;
}

// ---------------- pre-pass: X fp32 -> packed split-bf16 ---------------------
__global__ __launch_bounds__(256) void convert_x(
    const float* __restrict__ X, u16* __restrict__ Xh, u16* __restrict__ Xl) {
  int t = threadIdx.x;
  int mt = blockIdx.x >> 5, k0b = blockIdx.x & 31;
  size_t outbase = (size_t)blockIdx.x * 4096;
#pragma unroll
  for (int it = 0; it < 2; ++it) {
    int idx = t + it * 256;
    int m = idx & 127, kg = idx >> 7;
    const float* src = X + (size_t)(mt * 128 + m) * FDIM + k0b * 32 + kg * 8;
    float4 v0 = *(const float4*)src;
    float4 v1 = *(const float4*)(src + 4);
    float f[8] = {v0.x, v0.y, v0.z, v0.w, v1.x, v1.y, v1.z, v1.w};
    unsigned short h[8], l[8];
#pragma unroll
    for (int j = 0; j < 8; ++j) {
      h[j] = f32_to_bf16(f[j]);
      l[j] = f32_to_bf16(f[j] - bf16_to_f32(h[j]));
    }
    uint4 hv, lv;
    hv.x = h[0] | ((unsigned)h[1] << 16); hv.y = h[2] | ((unsigned)h[3] << 16);
    hv.z = h[4] | ((unsigned)h[5] << 16); hv.w = h[6] | ((unsigned)h[7] << 16);
    lv.x = l[0] | ((unsigned)l[1] << 16); lv.y = l[2] | ((unsigned)l[3] << 16);
    lv.z = l[4] | ((unsigned)l[5] << 16); lv.w = l[6] | ((unsigned)l[7] << 16);
    size_t off = outbase + (size_t)(kg * 128 + m) * 8;
    *(uint4*)&Xh[off] = hv;
    *(uint4*)&Xl[off] = lv;
  }
}

// ---------------- pre-pass: W1 fp32 -> transposed packed split-bf16 ---------
__global__ __launch_bounds__(256) void convert_w1(
    const float* __restrict__ W1, u16* __restrict__ Wh, u16* __restrict__ Wl) {
  int t = threadIdx.x;
  int nt = blockIdx.x >> 5, k0b = blockIdx.x & 31;
  size_t outbase = (size_t)blockIdx.x * 4096;
#pragma unroll
  for (int it = 0; it < 2; ++it) {
    int idx = t + it * 256;
    int n = idx & 127, kg = idx >> 7;
    float f[8];
#pragma unroll
    for (int j = 0; j < 8; ++j)
      f[j] = W1[(size_t)(k0b * 32 + kg * 8 + j) * HDIM + nt * 128 + n];
    unsigned short h[8], l[8];
#pragma unroll
    for (int j = 0; j < 8; ++j) {
      h[j] = f32_to_bf16(f[j]);
      l[j] = f32_to_bf16(f[j] - bf16_to_f32(h[j]));
    }
    uint4 hv, lv;
    hv.x = h[0] | ((unsigned)h[1] << 16); hv.y = h[2] | ((unsigned)h[3] << 16);
    hv.z = h[4] | ((unsigned)h[5] << 16); hv.w = h[6] | ((unsigned)h[7] << 16);
    lv.x = l[0] | ((unsigned)l[1] << 16); lv.y = l[2] | ((unsigned)l[3] << 16);
    lv.z = l[4] | ((unsigned)l[5] << 16); lv.w = l[6] | ((unsigned)l[7] << 16);
    size_t off = outbase + (size_t)(kg * 128 + n) * 8;
    *(uint4*)&Wh[off] = hv;
    *(uint4*)&Wl[off] = lv;
  }
}

// ---------------- pre-pass: W2 fp32 -> zero-padded [4096][64] ---------------
__global__ __launch_bounds__(256) void convert_w2(
    const float* __restrict__ W2, float* __restrict__ W2p) {
  int idx = blockIdx.x * 256 + threadIdx.x;    // grid 1024 -> 262144 elems
  int k = idx >> 6, n = idx & 63;
  W2p[idx] = (n < NMAT) ? W2[(size_t)k * NMAT + n] : 0.0f;
}

// ---------------- GEMM1 (split-bf16 MFMA): hT = leaky(x @ W1 + b1)^T --------
// 128x128 tile, BK=32, 4 waves, 48 MFMA per k-step; staging via
// global_load_lds width-16 only. Round-6 change: epilogue writes h
// TRANSPOSED (hT[col][row], stride = chunk rows) so gemm2's A-loads
// coalesce; acc regs r=0..3 are consecutive rows -> float4 stores.
__global__ __launch_bounds__(256) void gemm1_mfma(
    const u16* __restrict__ Ah_, const u16* __restrict__ Al_,
    const u16* __restrict__ Bh_, const u16* __restrict__ Bl_,
    const float* __restrict__ b1,
    float* __restrict__ HTout,         // chunk base [4096][stride] fp32
    int mt0, int stride) {             // m-tile offset of chunk; chunk rows
  __shared__ __align__(16) u16 Ah[4096];
  __shared__ __align__(16) u16 Al[4096];
  __shared__ __align__(16) u16 Bh[4096];
  __shared__ __align__(16) u16 Bl[4096];
  int t = threadIdx.x;
  int wave = t >> 6, lane = t & 63;
  int nt = blockIdx.x & 31;      // 4096/128 n-tiles
  int mtl = blockIdx.x >> 5;     // m-tile local to chunk
  int wm = wave >> 1, wn = wave & 1;
  int fr = lane & 15, fg = lane >> 4;

  f32x4 acc[4][4];
#pragma unroll
  for (int i = 0; i < 4; ++i)
#pragma unroll
    for (int j = 0; j < 4; ++j) acc[i][j] = (f32x4){0.f, 0.f, 0.f, 0.f};

  const u16* pAh = Ah_ + (size_t)(mt0 + mtl) * 32 * 4096;
  const u16* pAl = Al_ + (size_t)(mt0 + mtl) * 32 * 4096;
  const u16* pBh = Bh_ + (size_t)nt * 32 * 4096;
  const u16* pBl = Bl_ + (size_t)nt * 32 * 4096;
  int so = wave * 1024 + lane * 8;   // per-lane src offset (elems), call 0
  int ld = wave * 1024;              // wave-uniform LDS dest (elems)

  for (int k0b = 0; k0b < 32; ++k0b) {
    __syncthreads();                 // previous-iter fragment reads done
    size_t sb = (size_t)k0b * 4096;
    gload16(pAh + sb + so,       &Ah[ld]);
    gload16(pAh + sb + so + 512, &Ah[ld + 512]);
    gload16(pAl + sb + so,       &Al[ld]);
    gload16(pAl + sb + so + 512, &Al[ld + 512]);
    gload16(pBh + sb + so,       &Bh[ld]);
    gload16(pBh + sb + so + 512, &Bh[ld + 512]);
    gload16(pBl + sb + so,       &Bl[ld]);
    gload16(pBl + sb + so + 512, &Bl[ld + 512]);
    __syncthreads();                 // vmcnt(0) drained by compiler before barrier
    // ---- fragments + MFMA ----
    bf16x8 ah[4], al[4], bh[4], bl[4];
#pragma unroll
    for (int i = 0; i < 4; ++i) {
      int arow = (fg * 128 + wm * 64 + i * 16 + fr) * 8;
      ah[i] = *(const bf16x8*)&Ah[arow];
      al[i] = *(const bf16x8*)&Al[arow];
      int brow = (fg * 128 + wn * 64 + i * 16 + fr) * 8;
      bh[i] = *(const bf16x8*)&Bh[brow];
      bl[i] = *(const bf16x8*)&Bl[brow];
    }
#pragma unroll
    for (int i = 0; i < 4; ++i)
#pragma unroll
      for (int j = 0; j < 4; ++j)
        acc[i][j] = __builtin_amdgcn_mfma_f32_16x16x32_bf16(ah[i], bh[j], acc[i][j], 0, 0, 0);
#pragma unroll
    for (int i = 0; i < 4; ++i)
#pragma unroll
      for (int j = 0; j < 4; ++j)
        acc[i][j] = __builtin_amdgcn_mfma_f32_16x16x32_bf16(ah[i], bl[j], acc[i][j], 0, 0, 0);
#pragma unroll
    for (int i = 0; i < 4; ++i)
#pragma unroll
      for (int j = 0; j < 4; ++j)
        acc[i][j] = __builtin_amdgcn_mfma_f32_16x16x32_bf16(al[i], bh[j], acc[i][j], 0, 0, 0);
  }

  // Epilogue (transposed store): col=lane&15, row=(lane>>4)*4+reg [m89].
  // r=0..3 are consecutive rows -> one float4 store per (i,j), 16B-aligned
  // (rowb+i*16 is a multiple of 4; stride is a multiple of 128).
  int colb = nt * 128 + wn * 64 + fr;
  int rowb = mtl * 128 + wm * 64 + fg * 4;
#pragma unroll
  for (int j = 0; j < 4; ++j) {
    float bias = b1[colb + j * 16];
#pragma unroll
    for (int i = 0; i < 4; ++i) {
      float4 v4;
      float* vp = &v4.x;
#pragma unroll
      for (int r = 0; r < 4; ++r) {
        float v = acc[i][j][r] + bias;
        vp[r] = v >= 0.0f ? v : 0.01f * v;
      }
      *(float4*)&HTout[(size_t)(colb + j * 16) * stride + rowb + i * 16] = v4;
    }
  }
}

// ---------------- GEMM2 (fp64 MFMA, streaming, LDS/barrier-free) ------------
// 1 wave per block, 16 rows x K=512; grid (rows/16, NPART) = up to 3200
// blocks (~12/CU). A read direct from transposed hT (4x64B fully-used lines
// per load instr, one HBM pass); B from zero-padded L2-resident W2p. No LDS,
// no __syncthreads. Layout self-calibration kept verbatim (round-3 verified).
__global__ __launch_bounds__(64) void gemm2_mfma(
    const float* __restrict__ hT,     // chunk base [4096][stride] fp32
    const float* __restrict__ W2p,    // [4096][64] fp32 zero-padded
    double* __restrict__ Mpart,       // [NPART][6400][50]
    int row0, int stride) {
  int lane = threadIdx.x;
  int kz = blockIdx.y;
  int fr = lane & 15, fk = lane >> 4;

  // ---- layout calibration (4 MFMAs, once per block) ----
  f64x4 z4 = (f64x4){0.0, 0.0, 0.0, 0.0};
  f64x4 pA = __builtin_amdgcn_mfma_f64_16x16x4f64((double)lane, 1.0, z4, 0, 0, 0);
  f64x4 pB = __builtin_amdgcn_mfma_f64_16x16x4f64(1.0, (double)lane, z4, 0, 0, 0);
  int aAlt = ((int)pA[0]) & 3;       // 0: lane=16k+i, nonzero: lane=4i+k
  int bAlt = ((int)pB[0]) & 3;
  int ai = aAlt ? (lane >> 2) : fr;  // this lane's A operand (row, k) indices
  int ak = aAlt ? (lane & 3) : fk;
  int bj = bAlt ? (lane >> 2) : fr;  // this lane's B operand (col, k) indices
  int bk = bAlt ? (lane & 3) : fk;
  f64x4 p1 = __builtin_amdgcn_mfma_f64_16x16x4f64((double)ai, 1.0, z4, 0, 0, 0);
  f64x4 p2 = __builtin_amdgcn_mfma_f64_16x16x4f64(1.0, (double)bj, z4, 0, 0, 0);
  int di[4], dj[4];
#pragma unroll
  for (int r = 0; r < 4; ++r) {
    di[r] = (((int)p1[r]) >> 2) & 15;   // exact output row of acc reg r
    dj[r] = (((int)p2[r]) >> 2) & 15;   // exact output col of acc reg r
  }

  f64x4 acc[4];
#pragma unroll
  for (int nt = 0; nt < 4; ++nt) acc[nt] = z4;

  const float* hA = hT + blockIdx.x * 16 + ai;   // + k*stride per step
  const int kend = kz * (FDIM * 4 / NPART) + (FDIM * 4 / NPART);
#pragma unroll 4
  for (int k = kz * (FDIM * 4 / NPART); k < kend; k += 4) {
    double av = (double)hA[(size_t)(k + ak) * stride];
#pragma unroll
    for (int nt = 0; nt < 4; ++nt) {
      double bv = (double)W2p[(k + bk) * 64 + nt * 16 + bj];
      acc[nt] = __builtin_amdgcn_mfma_f64_16x16x4f64(av, bv, acc[nt], 0, 0, 0);
    }
  }

  double* Mout = Mpart + (size_t)kz * PSIZE;
  int rowbase = row0 + blockIdx.x * 16;
#pragma unroll
  for (int nt = 0; nt < 4; ++nt)
#pragma unroll
    for (int r = 0; r < 4; ++r) {
      int col = nt * 16 + dj[r];
      if (col < NMAT)
        Mout[(size_t)(rowbase + di[r]) * NMAT + col] = acc[nt][r];
    }
}

// ---------------- Fused Sinkhorn + Hungarian (fp64, one wave per batch) -----
// Merge NPART partials, P = exp(leaky(M+b2)), 5x row/col norm in LDS;
// Hungarian (exact reference replica incl. dead-minv) on LDS P; DPP min.
__global__ __launch_bounds__(64) void sinkhorn_hungarian(
    const double* __restrict__ Mpart, const float* __restrict__ b2,
    float* __restrict__ out_psi, float* __restrict__ out_X,
    float* __restrict__ out_perms, float* __restrict__ out_dist) {
  int b = blockIdx.x, lane = threadIdx.x;
  __shared__ double P[2500];
  __shared__ double cost[2500];
  __shared__ double rs[50];
  __shared__ double u[51];
  __shared__ int p[51];
  __shared__ int wayl[51];
  const size_t base = (size_t)b * 2500;

  // ---- Sinkhorn ----
  for (int e = lane; e < 2500; e += 64) {
    double m = 0.0;
#pragma unroll
    for (int pz = 0; pz < NPART; ++pz)
      m += Mpart[(size_t)pz * PSIZE + base + e];
    m += (double)b2[e % 50];
    m = m >= 0.0 ? m : 0.01 * m;      // leaky_relu in fp64
    P[e] = exp(m);                    // TAU = 1.0
  }
  __syncthreads();
  for (int it = 0; it < 5; ++it) {
    if (lane < 50) { double s = 0; for (int j = 0; j < 50; ++j) s += P[lane * 50 + j]; rs[lane] = s; }
    __syncthreads();
    for (int e = lane; e < 2500; e += 64) P[e] /= rs[e / 50];   // axis=2
    __syncthreads();
    if (lane < 50) { double s = 0; for (int r = 0; r < 50; ++r) s += P[r * 50 + lane]; rs[lane] = s; }
    __syncthreads();
    for (int e = lane; e < 2500; e += 64) P[e] /= rs[e % 50];   // axis=1
    __syncthreads();
  }
  for (int e = lane; e < 2500; e += 64) {
    float f = (float)P[e];
    out_psi[base + e] = f;
    out_X[base + e] = f;              // ALPHA=1.0 => X == psi exactly
    cost[e] = -P[e];
  }
  if (lane < 51) { u[lane] = 0.0; p[lane] = 0; }
  __syncthreads();

  // ---- Hungarian ----
  double v = 0.0;                      // v[lane+1]
  bool lactive = lane < NMAT;
  for (int i = 1; i <= NMAT; ++i) {
    bool used = false;
    int way = 0;
    int j0 = 0, j1 = 0;
    for (int guard = 0; guard < 64; ++guard) {   // defensive cap (normally <=51)
      if (lane == j0 - 1) used = true;           // used[j0] = True (j0>=1)
      int i0 = (j0 == 0) ? i : p[j0];
      double ui0 = u[i0];
      double cand = HINF;
      if (lactive && !used) {
        cand = cost[(i0 - 1) * NMAT + lane] - ui0 - v;
        way = j0;                                // way set for ALL free cols (dead-minv)
      }
      double m = wave_min_f64(cand);
      unsigned long long bal = __ballot(cand == m);
      j1 = (int)__builtin_ctzll(bal) + 1;        // np.argmin tie-break: lowest j
      double delta = m;
      __syncthreads();
      if (used) { v -= delta; u[p[lane + 1]] += delta; }   // distinct rows, no race
      if (lane == 63) u[i] += delta;                       // j=0 column: p[0]=i
      __syncthreads();
      j0 = j1;
      if (p[j0] == 0) break;
    }
    if (lactive) wayl[lane + 1] = way;
    __syncthreads();
    if (lane == 0) {                   // augment (serial; path <= 50, bounded)
      int j = j1;
      for (int step = 0; step < 64 && j != 0; ++step) {
        int jw = wayl[j];
        p[j] = (jw == 0) ? i : p[jw];
        j = jw;
      }
    }
    __syncthreads();
  }

  // perms one-hot + dist (fp32 outputs)
  size_t pbase = (size_t)b * 2500;
  for (int e = lane; e < 2500; e += 64) out_perms[pbase + e] = 0.0f;
  __syncthreads();
  double val = 0.0;
  if (lactive) {
    int row = p[lane + 1] - 1;
    if (row < 0) row = 0;              // defensive clamp (provably unreachable)
    if (row > 49) row = 49;
    out_perms[pbase + (size_t)row * NMAT + lane] = 1.0f;
    val = P[(size_t)row * NMAT + lane];
  }
#pragma unroll
  for (int s = 32; s > 0; s >>= 1) val += __shfl_xor(val, s, 64);
  if (lane == 0) out_dist[b] = (float)(val / (double)NMAT);
}

// ---------------------------------------------------------------------------
extern "C" void kernel_launch(void* const* d_in, const int* in_sizes, int n_in,
                              void* d_out, int out_size, void* d_ws, size_t ws_size,
                              hipStream_t stream) {
  const float* x  = (const float*)d_in[0];   // fp32 per the reference dtypes
  const float* W1 = (const float*)d_in[1];
  const float* b1 = (const float*)d_in[2];
  const float* W2 = (const float*)d_in[3];
  const float* b2 = (const float*)d_in[4];
  float* out = (float*)d_out;                // outputs float32 (round-8/11 finding)
  float* out_psi   = out;
  float* out_perms = out + PSIZE;
  float* out_X     = out + 2 * PSIZE;
  float* out_dist  = out + 3 * PSIZE;

  if (ws_size < (size_t)WS_MIN) return;

  char* ws = (char*)d_ws;
  double* Mpart = (double*)(ws + WS_M_OFF);
  u16* Xh  = (u16*)(ws + WS_XH_OFF);
  u16* Xl  = (u16*)(ws + WS_XL_OFF);
  u16* W1h = (u16*)(ws + WS_W1H_OFF);
  u16* W1l = (u16*)(ws + WS_W1L_OFF);
  float* W2p  = (float*)(ws + WS_W2P_OFF);
  float* hbuf = (float*)(ws + WS_H_OFF);
  long long avail = (long long)ws_size - WS_H_OFF;
  int max_rows = (int)(avail / (HDIM * 4));
  max_rows = (max_rows / 128) * 128;
  if (max_rows > ROWS) max_rows = ROWS;

  // one-time conversions: split-bf16 pack (X, W1) + zero-padded W2
  hipLaunchKernelGGL(convert_x, dim3(1600), dim3(256), 0, stream, x, Xh, Xl);
  hipLaunchKernelGGL(convert_w1, dim3(1024), dim3(256), 0, stream, W1, W1h, W1l);
  hipLaunchKernelGGL(convert_w2, dim3(1024), dim3(256), 0, stream, W2, W2p);

  for (int r0 = 0; r0 < ROWS; r0 += max_rows) {
    int rows = (ROWS - r0 < max_rows) ? (ROWS - r0) : max_rows;
    hipLaunchKernelGGL(gemm1_mfma, dim3((rows / 128) * 32), dim3(256), 0, stream,
                       Xh, Xl, W1h, W1l, b1, hbuf, r0 / 128, rows);
    hipLaunchKernelGGL(gemm2_mfma, dim3(rows / 16, NPART), dim3(64), 0, stream,
                       hbuf, W2p, Mpart, r0, rows);
  }
  hipLaunchKernelGGL(sinkhorn_hungarian, dim3(BATCH), dim3(64), 0, stream,
                     Mpart, b2, out_psi, out_X, out_perms, out_dist);
}

// Round 7
// 492.245 us; speedup vs baseline: 1.1402x; 1.1402x over previous
//
#include <hip/hip_runtime.h>

// Problem constants
#define NMAT 50
#define BATCH 128
#define FDIM 1024
#define HDIM 4096
#define ROWS 6400            // BATCH*NMAT
#define PSIZE 320000         // BATCH*NMAT*NMAT
#define NPART 4              // split-K partials for gemm2
#define HINF 1e18

// ws layout (bytes):
//   Mpart : fp32 [4][6400][50] split-K partials (5.12 MB)
//   Xh/Xl : packed split-bf16 X     [50 mt][32 k0b][4 kg][128 m][8] 13.1 MB each
//   W1h/l : packed split-bf16 W1^T  [32 nt][32 k0b][4 kg][128 n][8] 8.39 MB each
//   W2h/l : bf16 W2^T planes [64][4096] (cols>=50 zero), 512 KB each, L2-resident
//   hbuf  : u32 hT-packed [4096][max_rows]: (bf16hi<<16)|bf16lo of h^T
#define WS_M_OFF   0
#define WS_XH_OFF  5120000LL
#define WS_XL_OFF  18227200LL
#define WS_W1H_OFF 31334400LL
#define WS_W1L_OFF 39723008LL
#define WS_W2H_OFF 48111616LL
#define WS_W2L_OFF 48635904LL
#define WS_H_OFF   49160192LL
#define WS_MIN     (WS_H_OFF + 128LL * HDIM * 4)   // ~51.3 MB

typedef __bf16 bf16x8 __attribute__((ext_vector_type(8)));
typedef short short8 __attribute__((ext_vector_type(8)));
typedef float f32x4 __attribute__((ext_vector_type(4)));
typedef unsigned short u16;
typedef unsigned int u32;

__device__ __forceinline__ float bf16_to_f32(unsigned short h) {
  return __uint_as_float(((unsigned int)h) << 16);
}
__device__ __forceinline__ unsigned short f32_to_bf16(float f) {
  unsigned int u = __float_as_uint(f);
  u += 0x7FFFu + ((u >> 16) & 1u);   // RNE
  return (unsigned short)(u >> 16);
}

// async global->LDS, 16B per lane; LDS dest = wave-uniform base + lane*16
__device__ __forceinline__ void gload16(const u16* g, u16* l) {
  __builtin_amdgcn_global_load_lds(
      (const __attribute__((address_space(1))) unsigned int*)g,
      (__attribute__((address_space(3))) unsigned int*)l, 16, 0, 0);
}

// ---- wave-wide fp64 min via DPP (round-5/6 verified) ----
__device__ __forceinline__ double wave_min_f64(double x) {
  union { double d; int i[2]; } u, t;
  u.d = x;
#define DPP_MIN_STEP(ctrl)                                                   \
  t.i[0] = __builtin_amdgcn_update_dpp(u.i[0], u.i[0], ctrl, 0xf, 0xf, false);\
  t.i[1] = __builtin_amdgcn_update_dpp(u.i[1], u.i[1], ctrl, 0xf, 0xf, false);\
  u.d = fmin(u.d, t.d);
  DPP_MIN_STEP(0x111)  // row_shr:1
  DPP_MIN_STEP(0x112)  // row_shr:2
  DPP_MIN_STEP(0x114)  // row_shr:4
  DPP_MIN_STEP(0x118)  // row_shr:8
  DPP_MIN_STEP(0x142)  // row_bcast15
  DPP_MIN_STEP(0x143)  // row_bcast31
#undef DPP_MIN_STEP
  union { double d; int i[2]; } r;
  r.i[0] = __builtin_amdgcn_readlane(u.i[0], 63);
  r.i[1] = __builtin_amdgcn_readlane(u.i[1], 63);
  return r.d;
}

// ---------------- pre-pass: X fp32 -> packed split-bf16 ---------------------
__global__ __launch_bounds__(256) void convert_x(
    const float* __restrict__ X, u16* __restrict__ Xh, u16* __restrict__ Xl) {
  int t = threadIdx.x;
  int mt = blockIdx.x >> 5, k0b = blockIdx.x & 31;
  size_t outbase = (size_t)blockIdx.x * 4096;
#pragma unroll
  for (int it = 0; it < 2; ++it) {
    int idx = t + it * 256;
    int m = idx & 127, kg = idx >> 7;
    const float* src = X + (size_t)(mt * 128 + m) * FDIM + k0b * 32 + kg * 8;
    float4 v0 = *(const float4*)src;
    float4 v1 = *(const float4*)(src + 4);
    float f[8] = {v0.x, v0.y, v0.z, v0.w, v1.x, v1.y, v1.z, v1.w};
    unsigned short h[8], l[8];
#pragma unroll
    for (int j = 0; j < 8; ++j) {
      h[j] = f32_to_bf16(f[j]);
      l[j] = f32_to_bf16(f[j] - bf16_to_f32(h[j]));
    }
    uint4 hv, lv;
    hv.x = h[0] | ((unsigned)h[1] << 16); hv.y = h[2] | ((unsigned)h[3] << 16);
    hv.z = h[4] | ((unsigned)h[5] << 16); hv.w = h[6] | ((unsigned)h[7] << 16);
    lv.x = l[0] | ((unsigned)l[1] << 16); lv.y = l[2] | ((unsigned)l[3] << 16);
    lv.z = l[4] | ((unsigned)l[5] << 16); lv.w = l[6] | ((unsigned)l[7] << 16);
    size_t off = outbase + (size_t)(kg * 128 + m) * 8;
    *(uint4*)&Xh[off] = hv;
    *(uint4*)&Xl[off] = lv;
  }
}

// ---------------- pre-pass: W1 fp32 -> transposed packed split-bf16 ---------
__global__ __launch_bounds__(256) void convert_w1(
    const float* __restrict__ W1, u16* __restrict__ Wh, u16* __restrict__ Wl) {
  int t = threadIdx.x;
  int nt = blockIdx.x >> 5, k0b = blockIdx.x & 31;
  size_t outbase = (size_t)blockIdx.x * 4096;
#pragma unroll
  for (int it = 0; it < 2; ++it) {
    int idx = t + it * 256;
    int n = idx & 127, kg = idx >> 7;
    float f[8];
#pragma unroll
    for (int j = 0; j < 8; ++j)
      f[j] = W1[(size_t)(k0b * 32 + kg * 8 + j) * HDIM + nt * 128 + n];
    unsigned short h[8], l[8];
#pragma unroll
    for (int j = 0; j < 8; ++j) {
      h[j] = f32_to_bf16(f[j]);
      l[j] = f32_to_bf16(f[j] - bf16_to_f32(h[j]));
    }
    uint4 hv, lv;
    hv.x = h[0] | ((unsigned)h[1] << 16); hv.y = h[2] | ((unsigned)h[3] << 16);
    hv.z = h[4] | ((unsigned)h[5] << 16); hv.w = h[6] | ((unsigned)h[7] << 16);
    lv.x = l[0] | ((unsigned)l[1] << 16); lv.y = l[2] | ((unsigned)l[3] << 16);
    lv.z = l[4] | ((unsigned)l[5] << 16); lv.w = l[6] | ((unsigned)l[7] << 16);
    size_t off = outbase + (size_t)(kg * 128 + n) * 8;
    *(uint4*)&Wh[off] = hv;
    *(uint4*)&Wl[off] = lv;
  }
}

// ---------------- pre-pass: W2 fp32 -> transposed split-bf16 planes ---------
// W2T_hi/lo[n][k], n in [0,64) (cols >= 50 zero). Writes coalesced.
__global__ __launch_bounds__(256) void convert_w2(
    const float* __restrict__ W2, u16* __restrict__ W2h, u16* __restrict__ W2l) {
  int idx = blockIdx.x * 256 + threadIdx.x;   // grid 1024 -> 64*4096 elems
  int n = idx >> 12, k = idx & 4095;
  float f = (n < NMAT) ? W2[(size_t)k * NMAT + n] : 0.0f;
  unsigned short hi = f32_to_bf16(f);
  unsigned short lo = f32_to_bf16(f - bf16_to_f32(hi));
  W2h[idx] = hi;
  W2l[idx] = lo;
}

// ---------------- GEMM1 (split-bf16 MFMA): h = leaky(x @ W1 + b1) -----------
// 128x128 tile, BK=32, 4 waves, 48 MFMA per k-step; staging via
// global_load_lds width-16 only. Epilogue: h value split to (bf16hi,bf16lo),
// packed into one u32, stored TRANSPOSED hT[col][row] — identical uint4
// store addresses as the round-6 fp32 version (verified).
__global__ __launch_bounds__(256) void gemm1_mfma(
    const u16* __restrict__ Ah_, const u16* __restrict__ Al_,
    const u16* __restrict__ Bh_, const u16* __restrict__ Bl_,
    const float* __restrict__ b1,
    u32* __restrict__ HTout,           // chunk base [4096][stride] u32-packed
    int mt0, int stride) {             // m-tile offset of chunk; chunk rows
  __shared__ __align__(16) u16 Ah[4096];
  __shared__ __align__(16) u16 Al[4096];
  __shared__ __align__(16) u16 Bh[4096];
  __shared__ __align__(16) u16 Bl[4096];
  int t = threadIdx.x;
  int wave = t >> 6, lane = t & 63;
  int nt = blockIdx.x & 31;      // 4096/128 n-tiles
  int mtl = blockIdx.x >> 5;     // m-tile local to chunk
  int wm = wave >> 1, wn = wave & 1;
  int fr = lane & 15, fg = lane >> 4;

  f32x4 acc[4][4];
#pragma unroll
  for (int i = 0; i < 4; ++i)
#pragma unroll
    for (int j = 0; j < 4; ++j) acc[i][j] = (f32x4){0.f, 0.f, 0.f, 0.f};

  const u16* pAh = Ah_ + (size_t)(mt0 + mtl) * 32 * 4096;
  const u16* pAl = Al_ + (size_t)(mt0 + mtl) * 32 * 4096;
  const u16* pBh = Bh_ + (size_t)nt * 32 * 4096;
  const u16* pBl = Bl_ + (size_t)nt * 32 * 4096;
  int so = wave * 1024 + lane * 8;   // per-lane src offset (elems), call 0
  int ld = wave * 1024;              // wave-uniform LDS dest (elems)

  for (int k0b = 0; k0b < 32; ++k0b) {
    __syncthreads();                 // previous-iter fragment reads done
    size_t sb = (size_t)k0b * 4096;
    gload16(pAh + sb + so,       &Ah[ld]);
    gload16(pAh + sb + so + 512, &Ah[ld + 512]);
    gload16(pAl + sb + so,       &Al[ld]);
    gload16(pAl + sb + so + 512, &Al[ld + 512]);
    gload16(pBh + sb + so,       &Bh[ld]);
    gload16(pBh + sb + so + 512, &Bh[ld + 512]);
    gload16(pBl + sb + so,       &Bl[ld]);
    gload16(pBl + sb + so + 512, &Bl[ld + 512]);
    __syncthreads();                 // vmcnt(0) drained by compiler before barrier
    // ---- fragments + MFMA ----
    bf16x8 ah[4], al[4], bh[4], bl[4];
#pragma unroll
    for (int i = 0; i < 4; ++i) {
      int arow = (fg * 128 + wm * 64 + i * 16 + fr) * 8;
      ah[i] = *(const bf16x8*)&Ah[arow];
      al[i] = *(const bf16x8*)&Al[arow];
      int brow = (fg * 128 + wn * 64 + i * 16 + fr) * 8;
      bh[i] = *(const bf16x8*)&Bh[brow];
      bl[i] = *(const bf16x8*)&Bl[brow];
    }
#pragma unroll
    for (int i = 0; i < 4; ++i)
#pragma unroll
      for (int j = 0; j < 4; ++j)
        acc[i][j] = __builtin_amdgcn_mfma_f32_16x16x32_bf16(ah[i], bh[j], acc[i][j], 0, 0, 0);
#pragma unroll
    for (int i = 0; i < 4; ++i)
#pragma unroll
      for (int j = 0; j < 4; ++j)
        acc[i][j] = __builtin_amdgcn_mfma_f32_16x16x32_bf16(ah[i], bl[j], acc[i][j], 0, 0, 0);
#pragma unroll
    for (int i = 0; i < 4; ++i)
#pragma unroll
      for (int j = 0; j < 4; ++j)
        acc[i][j] = __builtin_amdgcn_mfma_f32_16x16x32_bf16(al[i], bh[j], acc[i][j], 0, 0, 0);
  }

  // Epilogue (transposed, split-bf16-packed store): col=lane&15,
  // row=(lane>>4)*4+reg [m89]. r=0..3 consecutive rows -> one uint4 store.
  int colb = nt * 128 + wn * 64 + fr;
  int rowb = mtl * 128 + wm * 64 + fg * 4;
#pragma unroll
  for (int j = 0; j < 4; ++j) {
    float bias = b1[colb + j * 16];
#pragma unroll
    for (int i = 0; i < 4; ++i) {
      uint4 pk;
      u32* pp = &pk.x;
#pragma unroll
      for (int r = 0; r < 4; ++r) {
        float v = acc[i][j][r] + bias;
        v = v >= 0.0f ? v : 0.01f * v;
        unsigned short hi = f32_to_bf16(v);
        unsigned short lo = f32_to_bf16(v - bf16_to_f32(hi));
        pp[r] = ((u32)hi << 16) | lo;
      }
      *(uint4*)&HTout[(size_t)(colb + j * 16) * stride + rowb + i * 16] = pk;
    }
  }
}

// ---------------- GEMM2 (split-bf16 MFMA, streaming): Mpart = h @ W2 --------
// The f64-MFMA path hit CDNA4's reduced fp64-matrix pipe (~165 us across two
// structures). Replaced with the SAME split-bf16 3-pass trick as gemm1, on
// the SAME m89-verified mfma_f32_16x16x32_bf16 — no layout probes needed.
// Error: dM ~ 5e-5 -> dpsi ~ 1e-6, 2+ orders below the validated 2.44e-4.
// 1 wave/block, 16 rows x 64 cols x K=1024 slice; grid (rows/16, NPART).
// A from packed hT (u32 = hi<<16|lo), unpacked in-reg; B from L2-resident
// W2T bf16 planes. ~614k MFMAs total + 105 MB h-read: HBM-bound ~20 us.
__global__ __launch_bounds__(64) void gemm2_bf16(
    const u32* __restrict__ hT,       // chunk base [4096][stride] u32-packed
    const u16* __restrict__ W2h,      // [64][4096] bf16 hi plane
    const u16* __restrict__ W2l,      // [64][4096] bf16 lo plane
    float* __restrict__ Mpart,        // [NPART][6400][50] fp32
    int row0, int stride) {
  int lane = threadIdx.x;
  int kz = blockIdx.y;
  int fr = lane & 15, fg = lane >> 4;

  f32x4 acc[4];
#pragma unroll
  for (int nt = 0; nt < 4; ++nt) acc[nt] = (f32x4){0.f, 0.f, 0.f, 0.f};

  const u32* hA = hT + blockIdx.x * 16 + fr;   // this lane's h-row (A row=fr)
  for (int ks = 0; ks < 32; ++ks) {
    int k0 = kz * 1024 + ks * 32;
    u32 hp[8];
#pragma unroll
    for (int kk = 0; kk < 8; ++kk)       // A frag: k = k0 + fg*8 + kk [m89]
      hp[kk] = hA[(size_t)(k0 + fg * 8 + kk) * stride];
    short8 hs, ls;
#pragma unroll
    for (int kk = 0; kk < 8; ++kk) {
      hs[kk] = (short)(hp[kk] >> 16);
      ls[kk] = (short)(hp[kk] & 0xffffu);
    }
    bf16x8 ah = *(bf16x8*)&hs;
    bf16x8 al = *(bf16x8*)&ls;
#pragma unroll
    for (int nt = 0; nt < 4; ++nt) {     // B frag: col=fr, k=k0+fg*8.. [m89]
      const size_t boff = (size_t)(nt * 16 + fr) * 4096 + k0 + fg * 8;
      bf16x8 bh = *(const bf16x8*)&W2h[boff];
      bf16x8 bl = *(const bf16x8*)&W2l[boff];
      acc[nt] = __builtin_amdgcn_mfma_f32_16x16x32_bf16(ah, bh, acc[nt], 0, 0, 0);
      acc[nt] = __builtin_amdgcn_mfma_f32_16x16x32_bf16(ah, bl, acc[nt], 0, 0, 0);
      acc[nt] = __builtin_amdgcn_mfma_f32_16x16x32_bf16(al, bh, acc[nt], 0, 0, 0);
    }
  }

  // D: col=lane&15, row=(lane>>4)*4+reg [m89]
  float* Mout = Mpart + (size_t)kz * PSIZE;
  int rowbase = row0 + blockIdx.x * 16 + fg * 4;
#pragma unroll
  for (int nt = 0; nt < 4; ++nt) {
    int col = nt * 16 + fr;
    if (col < NMAT) {
#pragma unroll
      for (int r = 0; r < 4; ++r)
        Mout[(size_t)(rowbase + r) * NMAT + col] = acc[nt][r];
    }
  }
}

// ---------------- Fused Sinkhorn + Hungarian (fp64, one wave per batch) -----
// Merge NPART fp32 partials in fp64, P = exp(leaky(M+b2)), 5x row/col norm in
// LDS; Hungarian (exact reference replica incl. dead-minv) on LDS P; DPP min.
__global__ __launch_bounds__(64) void sinkhorn_hungarian(
    const float* __restrict__ Mpart, const float* __restrict__ b2,
    float* __restrict__ out_psi, float* __restrict__ out_X,
    float* __restrict__ out_perms, float* __restrict__ out_dist) {
  int b = blockIdx.x, lane = threadIdx.x;
  __shared__ double P[2500];
  __shared__ double cost[2500];
  __shared__ double rs[50];
  __shared__ double u[51];
  __shared__ int p[51];
  __shared__ int wayl[51];
  const size_t base = (size_t)b * 2500;

  // ---- Sinkhorn ----
  for (int e = lane; e < 2500; e += 64) {
    double m = 0.0;
#pragma unroll
    for (int pz = 0; pz < NPART; ++pz)
      m += (double)Mpart[(size_t)pz * PSIZE + base + e];
    m += (double)b2[e % 50];
    m = m >= 0.0 ? m : 0.01 * m;      // leaky_relu in fp64
    P[e] = exp(m);                    // TAU = 1.0
  }
  __syncthreads();
  for (int it = 0; it < 5; ++it) {
    if (lane < 50) { double s = 0; for (int j = 0; j < 50; ++j) s += P[lane * 50 + j]; rs[lane] = s; }
    __syncthreads();
    for (int e = lane; e < 2500; e += 64) P[e] /= rs[e / 50];   // axis=2
    __syncthreads();
    if (lane < 50) { double s = 0; for (int r = 0; r < 50; ++r) s += P[r * 50 + lane]; rs[lane] = s; }
    __syncthreads();
    for (int e = lane; e < 2500; e += 64) P[e] /= rs[e % 50];   // axis=1
    __syncthreads();
  }
  for (int e = lane; e < 2500; e += 64) {
    float f = (float)P[e];
    out_psi[base + e] = f;
    out_X[base + e] = f;              // ALPHA=1.0 => X == psi exactly
    cost[e] = -P[e];
  }
  if (lane < 51) { u[lane] = 0.0; p[lane] = 0; }
  __syncthreads();

  // ---- Hungarian ----
  double v = 0.0;                      // v[lane+1]
  bool lactive = lane < NMAT;
  for (int i = 1; i <= NMAT; ++i) {
    bool used = false;
    int way = 0;
    int j0 = 0, j1 = 0;
    for (int guard = 0; guard < 64; ++guard) {   // defensive cap (normally <=51)
      if (lane == j0 - 1) used = true;           // used[j0] = True (j0>=1)
      int i0 = (j0 == 0) ? i : p[j0];
      double ui0 = u[i0];
      double cand = HINF;
      if (lactive && !used) {
        cand = cost[(i0 - 1) * NMAT + lane] - ui0 - v;
        way = j0;                                // way set for ALL free cols (dead-minv)
      }
      double m = wave_min_f64(cand);
      unsigned long long bal = __ballot(cand == m);
      j1 = (int)__builtin_ctzll(bal) + 1;        // np.argmin tie-break: lowest j
      double delta = m;
      __syncthreads();
      if (used) { v -= delta; u[p[lane + 1]] += delta; }   // distinct rows, no race
      if (lane == 63) u[i] += delta;                       // j=0 column: p[0]=i
      __syncthreads();
      j0 = j1;
      if (p[j0] == 0) break;
    }
    if (lactive) wayl[lane + 1] = way;
    __syncthreads();
    if (lane == 0) {                   // augment (serial; path <= 50, bounded)
      int j = j1;
      for (int step = 0; step < 64 && j != 0; ++step) {
        int jw = wayl[j];
        p[j] = (jw == 0) ? i : p[jw];
        j = jw;
      }
    }
    __syncthreads();
  }

  // perms one-hot + dist (fp32 outputs)
  size_t pbase = (size_t)b * 2500;
  for (int e = lane; e < 2500; e += 64) out_perms[pbase + e] = 0.0f;
  __syncthreads();
  double val = 0.0;
  if (lactive) {
    int row = p[lane + 1] - 1;
    if (row < 0) row = 0;              // defensive clamp (provably unreachable)
    if (row > 49) row = 49;
    out_perms[pbase + (size_t)row * NMAT + lane] = 1.0f;
    val = P[(size_t)row * NMAT + lane];
  }
#pragma unroll
  for (int s = 32; s > 0; s >>= 1) val += __shfl_xor(val, s, 64);
  if (lane == 0) out_dist[b] = (float)(val / (double)NMAT);
}

// ---------------------------------------------------------------------------
extern "C" void kernel_launch(void* const* d_in, const int* in_sizes, int n_in,
                              void* d_out, int out_size, void* d_ws, size_t ws_size,
                              hipStream_t stream) {
  const float* x  = (const float*)d_in[0];   // fp32 per the reference dtypes
  const float* W1 = (const float*)d_in[1];
  const float* b1 = (const float*)d_in[2];
  const float* W2 = (const float*)d_in[3];
  const float* b2 = (const float*)d_in[4];
  float* out = (float*)d_out;                // outputs float32 (round-8/11 finding)
  float* out_psi   = out;
  float* out_perms = out + PSIZE;
  float* out_X     = out + 2 * PSIZE;
  float* out_dist  = out + 3 * PSIZE;

  if (ws_size < (size_t)WS_MIN) return;

  char* ws = (char*)d_ws;
  float* Mpart = (float*)(ws + WS_M_OFF);
  u16* Xh  = (u16*)(ws + WS_XH_OFF);
  u16* Xl  = (u16*)(ws + WS_XL_OFF);
  u16* W1h = (u16*)(ws + WS_W1H_OFF);
  u16* W1l = (u16*)(ws + WS_W1L_OFF);
  u16* W2h = (u16*)(ws + WS_W2H_OFF);
  u16* W2l = (u16*)(ws + WS_W2L_OFF);
  u32* hbuf = (u32*)(ws + WS_H_OFF);
  long long avail = (long long)ws_size - WS_H_OFF;
  int max_rows = (int)(avail / (HDIM * 4));
  max_rows = (max_rows / 128) * 128;
  if (max_rows > ROWS) max_rows = ROWS;

  // one-time conversions: split-bf16 pack (X, W1) + split-bf16 W2^T planes
  hipLaunchKernelGGL(convert_x, dim3(1600), dim3(256), 0, stream, x, Xh, Xl);
  hipLaunchKernelGGL(convert_w1, dim3(1024), dim3(256), 0, stream, W1, W1h, W1l);
  hipLaunchKernelGGL(convert_w2, dim3(1024), dim3(256), 0, stream, W2, W2h, W2l);

  for (int r0 = 0; r0 < ROWS; r0 += max_rows) {
    int rows = (ROWS - r0 < max_rows) ? (ROWS - r0) : max_rows;
    hipLaunchKernelGGL(gemm1_mfma, dim3((rows / 128) * 32), dim3(256), 0, stream,
                       Xh, Xl, W1h, W1l, b1, hbuf, r0 / 128, rows);
    hipLaunchKernelGGL(gemm2_bf16, dim3(rows / 16, NPART), dim3(64), 0, stream,
                       hbuf, W2h, W2l, Mpart, r0, rows);
  }
  hipLaunchKernelGGL(sinkhorn_hungarian, dim3(BATCH), dim3(64), 0, stream,
                     Mpart, b2, out_psi, out_X, out_perms, out_dist);
}

// Round 11
// 474.594 us; speedup vs baseline: 1.1826x; 1.0372x over previous
//
#include <hip/hip_runtime.h>

// Problem constants
#define NMAT 50
#define BATCH 128
#define FDIM 1024
#define HDIM 4096
#define ROWS 6400            // BATCH*NMAT
#define PSIZE 320000         // BATCH*NMAT*NMAT
#define NPART 8              // split-K partials for gemm2
#define HINF 1e18

// ws layout (bytes):
//   Mpart : fp32 [8][6400][50] split-K partials (10.24 MB)
//   Xh/Xl : packed split-bf16 X     [50 mt][32 k0b][4 kg][128 m][8] 13.1 MB each
//   W1h/l : packed split-bf16 W1^T  [32 nt][32 k0b][4 kg][128 n][8] 8.39 MB each
//   W2h/l : bf16 W2^T planes [64][4096] (cols>=50 zero), 512 KB each, L2-resident
//   hbuf  : u32 hT-packed [4096][max_rows]: (bf16hi<<16)|bf16lo of h^T
#define WS_M_OFF   0
#define WS_XH_OFF  10240000LL
#define WS_XL_OFF  23347200LL
#define WS_W1H_OFF 36454400LL
#define WS_W1L_OFF 44843008LL
#define WS_W2H_OFF 53231616LL
#define WS_W2L_OFF 53755904LL
#define WS_H_OFF   54280192LL
#define WS_MIN     (WS_H_OFF + 128LL * HDIM * 4)   // ~56.4 MB

typedef __bf16 bf16x8 __attribute__((ext_vector_type(8)));
typedef short short8 __attribute__((ext_vector_type(8)));
typedef float f32x4 __attribute__((ext_vector_type(4)));
typedef unsigned short u16;
typedef unsigned int u32;

__device__ __forceinline__ float bf16_to_f32(unsigned short h) {
  return __uint_as_float(((unsigned int)h) << 16);
}
__device__ __forceinline__ unsigned short f32_to_bf16(float f) {
  unsigned int u = __float_as_uint(f);
  u += 0x7FFFu + ((u >> 16) & 1u);   // RNE
  return (unsigned short)(u >> 16);
}

// async global->LDS, 16B per lane; LDS dest = wave-uniform base + lane*16
__device__ __forceinline__ void gload16(const u16* g, u16* l) {
  __builtin_amdgcn_global_load_lds(
      (const __attribute__((address_space(1))) unsigned int*)g,
      (__attribute__((address_space(3))) unsigned int*)l, 16, 0, 0);
}

// ---- wave-wide fp64 min via DPP (round-5/6/7 verified) ----
__device__ __forceinline__ double wave_min_f64(double x) {
  union { double d; int i[2]; } u, t;
  u.d = x;
#define DPP_MIN_STEP(ctrl)                                                   \
  t.i[0] = __builtin_amdgcn_update_dpp(u.i[0], u.i[0], ctrl, 0xf, 0xf, false);\
  t.i[1] = __builtin_amdgcn_update_dpp(u.i[1], u.i[1], ctrl, 0xf, 0xf, false);\
  u.d = fmin(u.d, t.d);
  DPP_MIN_STEP(0x111)  // row_shr:1
  DPP_MIN_STEP(0x112)  // row_shr:2
  DPP_MIN_STEP(0x114)  // row_shr:4
  DPP_MIN_STEP(0x118)  // row_shr:8
  DPP_MIN_STEP(0x142)  // row_bcast15
  DPP_MIN_STEP(0x143)  // row_bcast31
#undef DPP_MIN_STEP
  union { double d; int i[2]; } r;
  r.i[0] = __builtin_amdgcn_readlane(u.i[0], 63);
  r.i[1] = __builtin_amdgcn_readlane(u.i[1], 63);
  return r.d;
}

// ---------------- pre-pass: X fp32 -> packed split-bf16 ---------------------
__global__ __launch_bounds__(256) void convert_x(
    const float* __restrict__ X, u16* __restrict__ Xh, u16* __restrict__ Xl) {
  int t = threadIdx.x;
  int mt = blockIdx.x >> 5, k0b = blockIdx.x & 31;
  size_t outbase = (size_t)blockIdx.x * 4096;
#pragma unroll
  for (int it = 0; it < 2; ++it) {
    int idx = t + it * 256;
    int m = idx & 127, kg = idx >> 7;
    const float* src = X + (size_t)(mt * 128 + m) * FDIM + k0b * 32 + kg * 8;
    float4 v0 = *(const float4*)src;
    float4 v1 = *(const float4*)(src + 4);
    float f[8] = {v0.x, v0.y, v0.z, v0.w, v1.x, v1.y, v1.z, v1.w};
    unsigned short h[8], l[8];
#pragma unroll
    for (int j = 0; j < 8; ++j) {
      h[j] = f32_to_bf16(f[j]);
      l[j] = f32_to_bf16(f[j] - bf16_to_f32(h[j]));
    }
    uint4 hv, lv;
    hv.x = h[0] | ((unsigned)h[1] << 16); hv.y = h[2] | ((unsigned)h[3] << 16);
    hv.z = h[4] | ((unsigned)h[5] << 16); hv.w = h[6] | ((unsigned)h[7] << 16);
    lv.x = l[0] | ((unsigned)l[1] << 16); lv.y = l[2] | ((unsigned)l[3] << 16);
    lv.z = l[4] | ((unsigned)l[5] << 16); lv.w = l[6] | ((unsigned)l[7] << 16);
    size_t off = outbase + (size_t)(kg * 128 + m) * 8;
    *(uint4*)&Xh[off] = hv;
    *(uint4*)&Xl[off] = lv;
  }
}

// ---------------- pre-pass: W1 fp32 -> transposed packed split-bf16 ---------
__global__ __launch_bounds__(256) void convert_w1(
    const float* __restrict__ W1, u16* __restrict__ Wh, u16* __restrict__ Wl) {
  int t = threadIdx.x;
  int nt = blockIdx.x >> 5, k0b = blockIdx.x & 31;
  size_t outbase = (size_t)blockIdx.x * 4096;
#pragma unroll
  for (int it = 0; it < 2; ++it) {
    int idx = t + it * 256;
    int n = idx & 127, kg = idx >> 7;
    float f[8];
#pragma unroll
    for (int j = 0; j < 8; ++j)
      f[j] = W1[(size_t)(k0b * 32 + kg * 8 + j) * HDIM + nt * 128 + n];
    unsigned short h[8], l[8];
#pragma unroll
    for (int j = 0; j < 8; ++j) {
      h[j] = f32_to_bf16(f[j]);
      l[j] = f32_to_bf16(f[j] - bf16_to_f32(h[j]));
    }
    uint4 hv, lv;
    hv.x = h[0] | ((unsigned)h[1] << 16); hv.y = h[2] | ((unsigned)h[3] << 16);
    hv.z = h[4] | ((unsigned)h[5] << 16); hv.w = h[6] | ((unsigned)h[7] << 16);
    lv.x = l[0] | ((unsigned)l[1] << 16); lv.y = l[2] | ((unsigned)l[3] << 16);
    lv.z = l[4] | ((unsigned)l[5] << 16); lv.w = l[6] | ((unsigned)l[7] << 16);
    size_t off = outbase + (size_t)(kg * 128 + n) * 8;
    *(uint4*)&Wh[off] = hv;
    *(uint4*)&Wl[off] = lv;
  }
}

// ---------------- pre-pass: W2 fp32 -> transposed split-bf16 planes ---------
__global__ __launch_bounds__(256) void convert_w2(
    const float* __restrict__ W2, u16* __restrict__ W2h, u16* __restrict__ W2l) {
  int idx = blockIdx.x * 256 + threadIdx.x;   // grid 1024 -> 64*4096 elems
  int n = idx >> 12, k = idx & 4095;
  float f = (n < NMAT) ? W2[(size_t)k * NMAT + n] : 0.0f;
  unsigned short hi = f32_to_bf16(f);
  unsigned short lo = f32_to_bf16(f - bf16_to_f32(hi));
  W2h[idx] = hi;
  W2l[idx] = lo;
}

// ---------------- GEMM1 (split-bf16 MFMA): h = leaky(x @ W1 + b1) -----------
// 128x128 tile, BK=32, 4 waves, 48 MFMA per k-step; staging via
// global_load_lds width-16 only. Epilogue: h split to (bf16hi,bf16lo) in one
// u32, stored TRANSPOSED hT[col][row] (uint4 stores). Round-7 verified.
__global__ __launch_bounds__(256) void gemm1_mfma(
    const u16* __restrict__ Ah_, const u16* __restrict__ Al_,
    const u16* __restrict__ Bh_, const u16* __restrict__ Bl_,
    const float* __restrict__ b1,
    u32* __restrict__ HTout,           // chunk base [4096][stride] u32-packed
    int mt0, int stride) {             // m-tile offset of chunk; chunk rows
  __shared__ __align__(16) u16 Ah[4096];
  __shared__ __align__(16) u16 Al[4096];
  __shared__ __align__(16) u16 Bh[4096];
  __shared__ __align__(16) u16 Bl[4096];
  int t = threadIdx.x;
  int wave = t >> 6, lane = t & 63;
  int nt = blockIdx.x & 31;      // 4096/128 n-tiles
  int mtl = blockIdx.x >> 5;     // m-tile local to chunk
  int wm = wave >> 1, wn = wave & 1;
  int fr = lane & 15, fg = lane >> 4;

  f32x4 acc[4][4];
#pragma unroll
  for (int i = 0; i < 4; ++i)
#pragma unroll
    for (int j = 0; j < 4; ++j) acc[i][j] = (f32x4){0.f, 0.f, 0.f, 0.f};

  const u16* pAh = Ah_ + (size_t)(mt0 + mtl) * 32 * 4096;
  const u16* pAl = Al_ + (size_t)(mt0 + mtl) * 32 * 4096;
  const u16* pBh = Bh_ + (size_t)nt * 32 * 4096;
  const u16* pBl = Bl_ + (size_t)nt * 32 * 4096;
  int so = wave * 1024 + lane * 8;   // per-lane src offset (elems), call 0
  int ld = wave * 1024;              // wave-uniform LDS dest (elems)

  for (int k0b = 0; k0b < 32; ++k0b) {
    __syncthreads();                 // previous-iter fragment reads done
    size_t sb = (size_t)k0b * 4096;
    gload16(pAh + sb + so,       &Ah[ld]);
    gload16(pAh + sb + so + 512, &Ah[ld + 512]);
    gload16(pAl + sb + so,       &Al[ld]);
    gload16(pAl + sb + so + 512, &Al[ld + 512]);
    gload16(pBh + sb + so,       &Bh[ld]);
    gload16(pBh + sb + so + 512, &Bh[ld + 512]);
    gload16(pBl + sb + so,       &Bl[ld]);
    gload16(pBl + sb + so + 512, &Bl[ld + 512]);
    __syncthreads();                 // vmcnt(0) drained by compiler before barrier
    // ---- fragments + MFMA ----
    bf16x8 ah[4], al[4], bh[4], bl[4];
#pragma unroll
    for (int i = 0; i < 4; ++i) {
      int arow = (fg * 128 + wm * 64 + i * 16 + fr) * 8;
      ah[i] = *(const bf16x8*)&Ah[arow];
      al[i] = *(const bf16x8*)&Al[arow];
      int brow = (fg * 128 + wn * 64 + i * 16 + fr) * 8;
      bh[i] = *(const bf16x8*)&Bh[brow];
      bl[i] = *(const bf16x8*)&Bl[brow];
    }
#pragma unroll
    for (int i = 0; i < 4; ++i)
#pragma unroll
      for (int j = 0; j < 4; ++j)
        acc[i][j] = __builtin_amdgcn_mfma_f32_16x16x32_bf16(ah[i], bh[j], acc[i][j], 0, 0, 0);
#pragma unroll
    for (int i = 0; i < 4; ++i)
#pragma unroll
      for (int j = 0; j < 4; ++j)
        acc[i][j] = __builtin_amdgcn_mfma_f32_16x16x32_bf16(ah[i], bl[j], acc[i][j], 0, 0, 0);
#pragma unroll
    for (int i = 0; i < 4; ++i)
#pragma unroll
      for (int j = 0; j < 4; ++j)
        acc[i][j] = __builtin_amdgcn_mfma_f32_16x16x32_bf16(al[i], bh[j], acc[i][j], 0, 0, 0);
  }

  // Epilogue (transposed, split-bf16-packed store): col=lane&15,
  // row=(lane>>4)*4+reg [m89]. r=0..3 consecutive rows -> one uint4 store.
  int colb = nt * 128 + wn * 64 + fr;
  int rowb = mtl * 128 + wm * 64 + fg * 4;
#pragma unroll
  for (int j = 0; j < 4; ++j) {
    float bias = b1[colb + j * 16];
#pragma unroll
    for (int i = 0; i < 4; ++i) {
      uint4 pk;
      u32* pp = &pk.x;
#pragma unroll
      for (int r = 0; r < 4; ++r) {
        float v = acc[i][j][r] + bias;
        v = v >= 0.0f ? v : 0.01f * v;
        unsigned short hi = f32_to_bf16(v);
        unsigned short lo = f32_to_bf16(v - bf16_to_f32(hi));
        pp[r] = ((u32)hi << 16) | lo;
      }
      *(uint4*)&HTout[(size_t)(colb + j * 16) * stride + rowb + i * 16] = pk;
    }
  }
}

// ---------------- GEMM2 (split-bf16 MFMA, streaming): Mpart = h @ W2 --------
// Numerics round-7-verified; NPART=8 + prefetch round-10-verified (psi
// passed). 1 wave/block, 16 rows x K=512 slice; 3200 waves ~3.1/SIMD.
__global__ __launch_bounds__(64) void gemm2_bf16(
    const u32* __restrict__ hT,       // chunk base [4096][stride] u32-packed
    const u16* __restrict__ W2h,      // [64][4096] bf16 hi plane
    const u16* __restrict__ W2l,      // [64][4096] bf16 lo plane
    float* __restrict__ Mpart,        // [NPART][6400][50] fp32
    int row0, int stride) {
  int lane = threadIdx.x;
  int kz = blockIdx.y;
  int fr = lane & 15, fg = lane >> 4;

  f32x4 acc[4];
#pragma unroll
  for (int nt = 0; nt < 4; ++nt) acc[nt] = (f32x4){0.f, 0.f, 0.f, 0.f};

  const u32* hA = hT + blockIdx.x * 16 + fr;   // this lane's h-row (A row=fr)
  const int kbase = kz * 512;                  // K slice per partial
  u32 hp[8];
#pragma unroll
  for (int kk = 0; kk < 8; ++kk)               // A frag: k = k0 + fg*8 + kk
    hp[kk] = hA[(size_t)(kbase + fg * 8 + kk) * stride];

  for (int ks = 0; ks < 16; ++ks) {
    int k0 = kbase + ks * 32;
    u32 hn[8];
    if (ks < 15) {                             // prefetch next k-step
#pragma unroll
      for (int kk = 0; kk < 8; ++kk)
        hn[kk] = hA[(size_t)(k0 + 32 + fg * 8 + kk) * stride];
    }
    short8 hs, ls;
#pragma unroll
    for (int kk = 0; kk < 8; ++kk) {
      hs[kk] = (short)(hp[kk] >> 16);
      ls[kk] = (short)(hp[kk] & 0xffffu);
    }
    bf16x8 ah = *(bf16x8*)&hs;
    bf16x8 al = *(bf16x8*)&ls;
#pragma unroll
    for (int nt = 0; nt < 4; ++nt) {           // B frag: col=fr, k=k0+fg*8..
      const size_t boff = (size_t)(nt * 16 + fr) * 4096 + k0 + fg * 8;
      bf16x8 bh = *(const bf16x8*)&W2h[boff];
      bf16x8 bl = *(const bf16x8*)&W2l[boff];
      acc[nt] = __builtin_amdgcn_mfma_f32_16x16x32_bf16(ah, bh, acc[nt], 0, 0, 0);
      acc[nt] = __builtin_amdgcn_mfma_f32_16x16x32_bf16(ah, bl, acc[nt], 0, 0, 0);
      acc[nt] = __builtin_amdgcn_mfma_f32_16x16x32_bf16(al, bh, acc[nt], 0, 0, 0);
    }
    if (ks < 15) {
#pragma unroll
      for (int kk = 0; kk < 8; ++kk) hp[kk] = hn[kk];
    }
  }

  // D: col=lane&15, row=(lane>>4)*4+reg [m89]
  float* Mout = Mpart + (size_t)kz * PSIZE;
  int rowbase = row0 + blockIdx.x * 16 + fg * 4;
#pragma unroll
  for (int nt = 0; nt < 4; ++nt) {
    int col = nt * 16 + fr;
    if (col < NMAT) {
#pragma unroll
      for (int r = 0; r < 4; ++r)
        Mout[(size_t)(rowbase + r) * NMAT + col] = acc[nt][r];
    }
  }
}

// ---------------- Fused Sinkhorn + Hungarian (fp64, one wave per batch) -----
// ROUND-7-PASSING Hungarian restored verbatim (LDS p/u/wayl + DPP min).
// Round-10's register-resident variant produced a wrong assignment (perms
// absmax 1.0 with correct psi) — suspected miscompile of readlane over
// divergently-written registers; reverted rather than debugged blind.
// Sinkhorn merges NPART fp32 partials in fp64 (round-10 psi-verified).
__global__ __launch_bounds__(64) void sinkhorn_hungarian(
    const float* __restrict__ Mpart, const float* __restrict__ b2,
    float* __restrict__ out_psi, float* __restrict__ out_X,
    float* __restrict__ out_perms, float* __restrict__ out_dist) {
  int b = blockIdx.x, lane = threadIdx.x;
  __shared__ double P[2500];
  __shared__ double cost[2500];
  __shared__ double rs[50];
  __shared__ double u[51];
  __shared__ int p[51];
  __shared__ int wayl[51];
  const size_t base = (size_t)b * 2500;

  // ---- Sinkhorn ----
  for (int e = lane; e < 2500; e += 64) {
    double m = 0.0;
#pragma unroll
    for (int pz = 0; pz < NPART; ++pz)
      m += (double)Mpart[(size_t)pz * PSIZE + base + e];
    m += (double)b2[e % 50];
    m = m >= 0.0 ? m : 0.01 * m;      // leaky_relu in fp64
    P[e] = exp(m);                    // TAU = 1.0
  }
  __syncthreads();
  for (int it = 0; it < 5; ++it) {
    if (lane < 50) { double s = 0; for (int j = 0; j < 50; ++j) s += P[lane * 50 + j]; rs[lane] = s; }
    __syncthreads();
    for (int e = lane; e < 2500; e += 64) P[e] /= rs[e / 50];   // axis=2
    __syncthreads();
    if (lane < 50) { double s = 0; for (int r = 0; r < 50; ++r) s += P[r * 50 + lane]; rs[lane] = s; }
    __syncthreads();
    for (int e = lane; e < 2500; e += 64) P[e] /= rs[e % 50];   // axis=1
    __syncthreads();
  }
  for (int e = lane; e < 2500; e += 64) {
    float f = (float)P[e];
    out_psi[base + e] = f;
    out_X[base + e] = f;              // ALPHA=1.0 => X == psi exactly
    cost[e] = -P[e];
  }
  if (lane < 51) { u[lane] = 0.0; p[lane] = 0; }
  __syncthreads();

  // ---- Hungarian (round-7-passing LDS version) ----
  double v = 0.0;                      // v[lane+1]
  bool lactive = lane < NMAT;
  for (int i = 1; i <= NMAT; ++i) {
    bool used = false;
    int way = 0;
    int j0 = 0, j1 = 0;
    for (int guard = 0; guard < 64; ++guard) {   // defensive cap (normally <=51)
      if (lane == j0 - 1) used = true;           // used[j0] = True (j0>=1)
      int i0 = (j0 == 0) ? i : p[j0];
      double ui0 = u[i0];
      double cand = HINF;
      if (lactive && !used) {
        cand = cost[(i0 - 1) * NMAT + lane] - ui0 - v;
        way = j0;                                // dead-minv replica
      }
      double m = wave_min_f64(cand);
      unsigned long long bal = __ballot(cand == m);
      j1 = (int)__builtin_ctzll(bal) + 1;        // np.argmin tie-break: lowest j
      double delta = m;
      __syncthreads();
      if (used) { v -= delta; u[p[lane + 1]] += delta; }   // distinct rows, no race
      if (lane == 63) u[i] += delta;                       // j=0 column: p[0]=i
      __syncthreads();
      j0 = j1;
      if (p[j0] == 0) break;
    }
    if (lactive) wayl[lane + 1] = way;
    __syncthreads();
    if (lane == 0) {                   // augment (serial; path <= 50, bounded)
      int j = j1;
      for (int step = 0; step < 64 && j != 0; ++step) {
        int jw = wayl[j];
        p[j] = (jw == 0) ? i : p[jw];
        j = jw;
      }
    }
    __syncthreads();
  }

  // perms one-hot + dist (fp32 outputs)
  size_t pbase = (size_t)b * 2500;
  for (int e = lane; e < 2500; e += 64) out_perms[pbase + e] = 0.0f;
  __syncthreads();
  double val = 0.0;
  if (lactive) {
    int row = p[lane + 1] - 1;
    if (row < 0) row = 0;              // defensive clamp (provably unreachable)
    if (row > 49) row = 49;
    out_perms[pbase + (size_t)row * NMAT + lane] = 1.0f;
    val = P[(size_t)row * NMAT + lane];
  }
#pragma unroll
  for (int s = 32; s > 0; s >>= 1) val += __shfl_xor(val, s, 64);
  if (lane == 0) out_dist[b] = (float)(val / (double)NMAT);
}

// ---------------------------------------------------------------------------
extern "C" void kernel_launch(void* const* d_in, const int* in_sizes, int n_in,
                              void* d_out, int out_size, void* d_ws, size_t ws_size,
                              hipStream_t stream) {
  const float* x  = (const float*)d_in[0];   // fp32 per the reference dtypes
  const float* W1 = (const float*)d_in[1];
  const float* b1 = (const float*)d_in[2];
  const float* W2 = (const float*)d_in[3];
  const float* b2 = (const float*)d_in[4];
  float* out = (float*)d_out;                // outputs float32 (round-8/11 finding)
  float* out_psi   = out;
  float* out_perms = out + PSIZE;
  float* out_X     = out + 2 * PSIZE;
  float* out_dist  = out + 3 * PSIZE;

  if (ws_size < (size_t)WS_MIN) return;

  char* ws = (char*)d_ws;
  float* Mpart = (float*)(ws + WS_M_OFF);
  u16* Xh  = (u16*)(ws + WS_XH_OFF);
  u16* Xl  = (u16*)(ws + WS_XL_OFF);
  u16* W1h = (u16*)(ws + WS_W1H_OFF);
  u16* W1l = (u16*)(ws + WS_W1L_OFF);
  u16* W2h = (u16*)(ws + WS_W2H_OFF);
  u16* W2l = (u16*)(ws + WS_W2L_OFF);
  u32* hbuf = (u32*)(ws + WS_H_OFF);
  long long avail = (long long)ws_size - WS_H_OFF;
  int max_rows = (int)(avail / (HDIM * 4));
  max_rows = (max_rows / 128) * 128;
  if (max_rows > ROWS) max_rows = ROWS;

  // one-time conversions: split-bf16 pack (X, W1) + split-bf16 W2^T planes
  hipLaunchKernelGGL(convert_x, dim3(1600), dim3(256), 0, stream, x, Xh, Xl);
  hipLaunchKernelGGL(convert_w1, dim3(1024), dim3(256), 0, stream, W1, W1h, W1l);
  hipLaunchKernelGGL(convert_w2, dim3(1024), dim3(256), 0, stream, W2, W2h, W2l);

  for (int r0 = 0; r0 < ROWS; r0 += max_rows) {
    int rows = (ROWS - r0 < max_rows) ? (ROWS - r0) : max_rows;
    hipLaunchKernelGGL(gemm1_mfma, dim3((rows / 128) * 32), dim3(256), 0, stream,
                       Xh, Xl, W1h, W1l, b1, hbuf, r0 / 128, rows);
    hipLaunchKernelGGL(gemm2_bf16, dim3(rows / 16, NPART), dim3(64), 0, stream,
                       hbuf, W2h, W2l, Mpart, r0, rows);
  }
  hipLaunchKernelGGL(sinkhorn_hungarian, dim3(BATCH), dim3(64), 0, stream,
                     Mpart, b2, out_psi, out_X, out_perms, out_dist);
}

// Round 12
// 460.843 us; speedup vs baseline: 1.2179x; 1.0298x over previous
//
#include <hip/hip_runtime.h>

// Problem constants
#define NMAT 50
#define BATCH 128
#define FDIM 1024
#define HDIM 4096
#define ROWS 6400            // BATCH*NMAT
#define PSIZE 320000         // BATCH*NMAT*NMAT
#define NPART 16             // split-K partials for gemm2
#define HINF 1e18

// ws layout (bytes):
//   Mpart : fp32 [16][6400][50] split-K partials (20.48 MB)
//   Xh/Xl : packed split-bf16 X     [50 mt][32 k0b][4 kg][128 m][8] 13.1 MB each
//   W1h/l : packed split-bf16 W1^T  [32 nt][32 k0b][4 kg][128 n][8] 8.39 MB each
//   W2h/l : bf16 W2^T planes [64][4096] (cols>=50 zero), 512 KB each, L2-resident
//   hbuf  : u32 hT-packed [4096][max_rows]: (bf16hi<<16)|bf16lo of h^T
#define WS_M_OFF   0
#define WS_XH_OFF  20480000LL
#define WS_XL_OFF  33587200LL
#define WS_W1H_OFF 46694400LL
#define WS_W1L_OFF 55083008LL
#define WS_W2H_OFF 63471616LL
#define WS_W2L_OFF 63995904LL
#define WS_H_OFF   64520192LL
#define WS_MIN     (WS_H_OFF + 128LL * HDIM * 4)   // ~66.6 MB

typedef __bf16 bf16x8 __attribute__((ext_vector_type(8)));
typedef short short8 __attribute__((ext_vector_type(8)));
typedef float f32x4 __attribute__((ext_vector_type(4)));
typedef unsigned short u16;
typedef unsigned int u32;

__device__ __forceinline__ float bf16_to_f32(unsigned short h) {
  return __uint_as_float(((unsigned int)h) << 16);
}
__device__ __forceinline__ unsigned short f32_to_bf16(float f) {
  unsigned int u = __float_as_uint(f);
  u += 0x7FFFu + ((u >> 16) & 1u);   // RNE
  return (unsigned short)(u >> 16);
}

// async global->LDS, 16B per lane; LDS dest = wave-uniform base + lane*16
__device__ __forceinline__ void gload16(const u16* g, u16* l) {
  __builtin_amdgcn_global_load_lds(
      (const __attribute__((address_space(1))) unsigned int*)g,
      (__attribute__((address_space(3))) unsigned int*)l, 16, 0, 0);
}

// ---- wave-wide fp64 min via DPP (round-5/6/7/11 verified) ----
__device__ __forceinline__ double wave_min_f64(double x) {
  union { double d; int i[2]; } u, t;
  u.d = x;
#define DPP_MIN_STEP(ctrl)                                                   \
  t.i[0] = __builtin_amdgcn_update_dpp(u.i[0], u.i[0], ctrl, 0xf, 0xf, false);\
  t.i[1] = __builtin_amdgcn_update_dpp(u.i[1], u.i[1], ctrl, 0xf, 0xf, false);\
  u.d = fmin(u.d, t.d);
  DPP_MIN_STEP(0x111)  // row_shr:1
  DPP_MIN_STEP(0x112)  // row_shr:2
  DPP_MIN_STEP(0x114)  // row_shr:4
  DPP_MIN_STEP(0x118)  // row_shr:8
  DPP_MIN_STEP(0x142)  // row_bcast15
  DPP_MIN_STEP(0x143)  // row_bcast31
#undef DPP_MIN_STEP
  union { double d; int i[2]; } r;
  r.i[0] = __builtin_amdgcn_readlane(u.i[0], 63);
  r.i[1] = __builtin_amdgcn_readlane(u.i[1], 63);
  return r.d;
}

// ---- f64 broadcast-read of one lane's value (uniform index) ----
__device__ __forceinline__ double readlane_f64(double x, int l) {
  union { double d; int i2[2]; } a, b;
  a.d = x;
  b.i2[0] = __builtin_amdgcn_readlane(a.i2[0], l);
  b.i2[1] = __builtin_amdgcn_readlane(a.i2[1], l);
  return b.d;
}

// ---------------- pre-pass: X fp32 -> packed split-bf16 ---------------------
__global__ __launch_bounds__(256) void convert_x(
    const float* __restrict__ X, u16* __restrict__ Xh, u16* __restrict__ Xl) {
  int t = threadIdx.x;
  int mt = blockIdx.x >> 5, k0b = blockIdx.x & 31;
  size_t outbase = (size_t)blockIdx.x * 4096;
#pragma unroll
  for (int it = 0; it < 2; ++it) {
    int idx = t + it * 256;
    int m = idx & 127, kg = idx >> 7;
    const float* src = X + (size_t)(mt * 128 + m) * FDIM + k0b * 32 + kg * 8;
    float4 v0 = *(const float4*)src;
    float4 v1 = *(const float4*)(src + 4);
    float f[8] = {v0.x, v0.y, v0.z, v0.w, v1.x, v1.y, v1.z, v1.w};
    unsigned short h[8], l[8];
#pragma unroll
    for (int j = 0; j < 8; ++j) {
      h[j] = f32_to_bf16(f[j]);
      l[j] = f32_to_bf16(f[j] - bf16_to_f32(h[j]));
    }
    uint4 hv, lv;
    hv.x = h[0] | ((unsigned)h[1] << 16); hv.y = h[2] | ((unsigned)h[3] << 16);
    hv.z = h[4] | ((unsigned)h[5] << 16); hv.w = h[6] | ((unsigned)h[7] << 16);
    lv.x = l[0] | ((unsigned)l[1] << 16); lv.y = l[2] | ((unsigned)l[3] << 16);
    lv.z = l[4] | ((unsigned)l[5] << 16); lv.w = l[6] | ((unsigned)l[7] << 16);
    size_t off = outbase + (size_t)(kg * 128 + m) * 8;
    *(uint4*)&Xh[off] = hv;
    *(uint4*)&Xl[off] = lv;
  }
}

// ---------------- pre-pass: W1 fp32 -> transposed packed split-bf16 ---------
__global__ __launch_bounds__(256) void convert_w1(
    const float* __restrict__ W1, u16* __restrict__ Wh, u16* __restrict__ Wl) {
  int t = threadIdx.x;
  int nt = blockIdx.x >> 5, k0b = blockIdx.x & 31;
  size_t outbase = (size_t)blockIdx.x * 4096;
#pragma unroll
  for (int it = 0; it < 2; ++it) {
    int idx = t + it * 256;
    int n = idx & 127, kg = idx >> 7;
    float f[8];
#pragma unroll
    for (int j = 0; j < 8; ++j)
      f[j] = W1[(size_t)(k0b * 32 + kg * 8 + j) * HDIM + nt * 128 + n];
    unsigned short h[8], l[8];
#pragma unroll
    for (int j = 0; j < 8; ++j) {
      h[j] = f32_to_bf16(f[j]);
      l[j] = f32_to_bf16(f[j] - bf16_to_f32(h[j]));
    }
    uint4 hv, lv;
    hv.x = h[0] | ((unsigned)h[1] << 16); hv.y = h[2] | ((unsigned)h[3] << 16);
    hv.z = h[4] | ((unsigned)h[5] << 16); hv.w = h[6] | ((unsigned)h[7] << 16);
    lv.x = l[0] | ((unsigned)l[1] << 16); lv.y = l[2] | ((unsigned)l[3] << 16);
    lv.z = l[4] | ((unsigned)l[5] << 16); lv.w = l[6] | ((unsigned)l[7] << 16);
    size_t off = outbase + (size_t)(kg * 128 + n) * 8;
    *(uint4*)&Wh[off] = hv;
    *(uint4*)&Wl[off] = lv;
  }
}

// ---------------- pre-pass: W2 fp32 -> transposed split-bf16 planes ---------
__global__ __launch_bounds__(256) void convert_w2(
    const float* __restrict__ W2, u16* __restrict__ W2h, u16* __restrict__ W2l) {
  int idx = blockIdx.x * 256 + threadIdx.x;   // grid 1024 -> 64*4096 elems
  int n = idx >> 12, k = idx & 4095;
  float f = (n < NMAT) ? W2[(size_t)k * NMAT + n] : 0.0f;
  unsigned short hi = f32_to_bf16(f);
  unsigned short lo = f32_to_bf16(f - bf16_to_f32(hi));
  W2h[idx] = hi;
  W2l[idx] = lo;
}

// ---------------- GEMM1 (split-bf16 MFMA): h = leaky(x @ W1 + b1) -----------
// 128x128 tile, BK=32, 4 waves, 48 MFMA per k-step; staging via
// global_load_lds width-16 only. Epilogue: h split to (bf16hi,bf16lo) in one
// u32, stored TRANSPOSED hT[col][row] (uint4 stores). Round-7 verified.
__global__ __launch_bounds__(256) void gemm1_mfma(
    const u16* __restrict__ Ah_, const u16* __restrict__ Al_,
    const u16* __restrict__ Bh_, const u16* __restrict__ Bl_,
    const float* __restrict__ b1,
    u32* __restrict__ HTout,           // chunk base [4096][stride] u32-packed
    int mt0, int stride) {             // m-tile offset of chunk; chunk rows
  __shared__ __align__(16) u16 Ah[4096];
  __shared__ __align__(16) u16 Al[4096];
  __shared__ __align__(16) u16 Bh[4096];
  __shared__ __align__(16) u16 Bl[4096];
  int t = threadIdx.x;
  int wave = t >> 6, lane = t & 63;
  int nt = blockIdx.x & 31;      // 4096/128 n-tiles
  int mtl = blockIdx.x >> 5;     // m-tile local to chunk
  int wm = wave >> 1, wn = wave & 1;
  int fr = lane & 15, fg = lane >> 4;

  f32x4 acc[4][4];
#pragma unroll
  for (int i = 0; i < 4; ++i)
#pragma unroll
    for (int j = 0; j < 4; ++j) acc[i][j] = (f32x4){0.f, 0.f, 0.f, 0.f};

  const u16* pAh = Ah_ + (size_t)(mt0 + mtl) * 32 * 4096;
  const u16* pAl = Al_ + (size_t)(mt0 + mtl) * 32 * 4096;
  const u16* pBh = Bh_ + (size_t)nt * 32 * 4096;
  const u16* pBl = Bl_ + (size_t)nt * 32 * 4096;
  int so = wave * 1024 + lane * 8;   // per-lane src offset (elems), call 0
  int ld = wave * 1024;              // wave-uniform LDS dest (elems)

  for (int k0b = 0; k0b < 32; ++k0b) {
    __syncthreads();                 // previous-iter fragment reads done
    size_t sb = (size_t)k0b * 4096;
    gload16(pAh + sb + so,       &Ah[ld]);
    gload16(pAh + sb + so + 512, &Ah[ld + 512]);
    gload16(pAl + sb + so,       &Al[ld]);
    gload16(pAl + sb + so + 512, &Al[ld + 512]);
    gload16(pBh + sb + so,       &Bh[ld]);
    gload16(pBh + sb + so + 512, &Bh[ld + 512]);
    gload16(pBl + sb + so,       &Bl[ld]);
    gload16(pBl + sb + so + 512, &Bl[ld + 512]);
    __syncthreads();                 // vmcnt(0) drained by compiler before barrier
    // ---- fragments + MFMA ----
    bf16x8 ah[4], al[4], bh[4], bl[4];
#pragma unroll
    for (int i = 0; i < 4; ++i) {
      int arow = (fg * 128 + wm * 64 + i * 16 + fr) * 8;
      ah[i] = *(const bf16x8*)&Ah[arow];
      al[i] = *(const bf16x8*)&Al[arow];
      int brow = (fg * 128 + wn * 64 + i * 16 + fr) * 8;
      bh[i] = *(const bf16x8*)&Bh[brow];
      bl[i] = *(const bf16x8*)&Bl[brow];
    }
#pragma unroll
    for (int i = 0; i < 4; ++i)
#pragma unroll
      for (int j = 0; j < 4; ++j)
        acc[i][j] = __builtin_amdgcn_mfma_f32_16x16x32_bf16(ah[i], bh[j], acc[i][j], 0, 0, 0);
#pragma unroll
    for (int i = 0; i < 4; ++i)
#pragma unroll
      for (int j = 0; j < 4; ++j)
        acc[i][j] = __builtin_amdgcn_mfma_f32_16x16x32_bf16(ah[i], bl[j], acc[i][j], 0, 0, 0);
#pragma unroll
    for (int i = 0; i < 4; ++i)
#pragma unroll
      for (int j = 0; j < 4; ++j)
        acc[i][j] = __builtin_amdgcn_mfma_f32_16x16x32_bf16(al[i], bh[j], acc[i][j], 0, 0, 0);
  }

  // Epilogue (transposed, split-bf16-packed store): col=lane&15,
  // row=(lane>>4)*4+reg [m89]. r=0..3 consecutive rows -> one uint4 store.
  int colb = nt * 128 + wn * 64 + fr;
  int rowb = mtl * 128 + wm * 64 + fg * 4;
#pragma unroll
  for (int j = 0; j < 4; ++j) {
    float bias = b1[colb + j * 16];
#pragma unroll
    for (int i = 0; i < 4; ++i) {
      uint4 pk;
      u32* pp = &pk.x;
#pragma unroll
      for (int r = 0; r < 4; ++r) {
        float v = acc[i][j][r] + bias;
        v = v >= 0.0f ? v : 0.01f * v;
        unsigned short hi = f32_to_bf16(v);
        unsigned short lo = f32_to_bf16(v - bf16_to_f32(hi));
        pp[r] = ((u32)hi << 16) | lo;
      }
      *(uint4*)&HTout[(size_t)(colb + j * 16) * stride + rowb + i * 16] = pk;
    }
  }
}

// ---------------- GEMM2 (split-bf16 MFMA, streaming): Mpart = h @ W2 --------
// Numerics round-7/10-verified. Round-12: NPART 8->16 (6400 waves ~6.25/SIMD)
// + 2-deep A prefetch — pure TLP/ILP against the ~500cy exposed load latency.
// fp32-partial regrouping only (merge stays fp64 in sinkhorn).
__global__ __launch_bounds__(64) void gemm2_bf16(
    const u32* __restrict__ hT,       // chunk base [4096][stride] u32-packed
    const u16* __restrict__ W2h,      // [64][4096] bf16 hi plane
    const u16* __restrict__ W2l,      // [64][4096] bf16 lo plane
    float* __restrict__ Mpart,        // [NPART][6400][50] fp32
    int row0, int stride) {
  int lane = threadIdx.x;
  int kz = blockIdx.y;
  int fr = lane & 15, fg = lane >> 4;

  f32x4 acc[4];
#pragma unroll
  for (int nt = 0; nt < 4; ++nt) acc[nt] = (f32x4){0.f, 0.f, 0.f, 0.f};

  const u32* hA = hT + blockIdx.x * 16 + fr;   // this lane's h-row (A row=fr)
  const int kbase = kz * 256;                  // K slice per partial
  u32 hp[8], hn[8];
#pragma unroll
  for (int kk = 0; kk < 8; ++kk)               // A frag: k = k0 + fg*8 + kk
    hp[kk] = hA[(size_t)(kbase + fg * 8 + kk) * stride];
#pragma unroll
  for (int kk = 0; kk < 8; ++kk)
    hn[kk] = hA[(size_t)(kbase + 32 + fg * 8 + kk) * stride];

  for (int ks = 0; ks < 8; ++ks) {
    int k0 = kbase + ks * 32;
    u32 h2[8];
    if (ks < 6) {                              // prefetch depth-2
#pragma unroll
      for (int kk = 0; kk < 8; ++kk)
        h2[kk] = hA[(size_t)(k0 + 64 + fg * 8 + kk) * stride];
    }
    short8 hs, ls;
#pragma unroll
    for (int kk = 0; kk < 8; ++kk) {
      hs[kk] = (short)(hp[kk] >> 16);
      ls[kk] = (short)(hp[kk] & 0xffffu);
    }
    bf16x8 ah = *(bf16x8*)&hs;
    bf16x8 al = *(bf16x8*)&ls;
#pragma unroll
    for (int nt = 0; nt < 4; ++nt) {           // B frag: col=fr, k=k0+fg*8..
      const size_t boff = (size_t)(nt * 16 + fr) * 4096 + k0 + fg * 8;
      bf16x8 bh = *(const bf16x8*)&W2h[boff];
      bf16x8 bl = *(const bf16x8*)&W2l[boff];
      acc[nt] = __builtin_amdgcn_mfma_f32_16x16x32_bf16(ah, bh, acc[nt], 0, 0, 0);
      acc[nt] = __builtin_amdgcn_mfma_f32_16x16x32_bf16(ah, bl, acc[nt], 0, 0, 0);
      acc[nt] = __builtin_amdgcn_mfma_f32_16x16x32_bf16(al, bh, acc[nt], 0, 0, 0);
    }
    if (ks < 7) {
#pragma unroll
      for (int kk = 0; kk < 8; ++kk) hp[kk] = hn[kk];
    }
    if (ks < 6) {
#pragma unroll
      for (int kk = 0; kk < 8; ++kk) hn[kk] = h2[kk];
    }
  }

  // D: col=lane&15, row=(lane>>4)*4+reg [m89]
  float* Mout = Mpart + (size_t)kz * PSIZE;
  int rowbase = row0 + blockIdx.x * 16 + fg * 4;
#pragma unroll
  for (int nt = 0; nt < 4; ++nt) {
    int col = nt * 16 + fr;
    if (col < NMAT) {
#pragma unroll
      for (int r = 0; r < 4; ++r)
        Mout[(size_t)(rowbase + r) * NMAT + col] = acc[nt][r];
    }
  }
}

// ---------------- Fused Sinkhorn + Hungarian (fp64, one wave per batch) -----
// Sinkhorn unchanged. Hungarian round-12: READ-SIDE registerization of the
// round-7/11-passing LDS version. Provable invariants of one inner loop:
// (a) p never changes (augment is after the loop); (b) u[i0] of the current
// row never changes (a row joins the tree once; updates touch only tree
// rows); (c) v[j] of FREE columns never changes (only used cols decrement).
// => cache p,u into UNIFORMLY-written per-lane registers at outer-iter start
// (pc on lane j = p[j]; uc on lane r-1 = u[r]) and read via readlane; defer
// all u-writes to end-of-loop (uacc per used lane, total for row i) hitting
// the SAME LDS targets as round-7 (u[p[lane+1]] for used lanes, u[i]).
// Inner loop: zero LDS writes, zero barriers; only the cost-row LDS read
// remains on the ~250cy/step critical path (was ~600). Unlike round-10's
// failed variant, NO cross-lane reads of divergently-written registers.
__global__ __launch_bounds__(64) void sinkhorn_hungarian(
    const float* __restrict__ Mpart, const float* __restrict__ b2,
    float* __restrict__ out_psi, float* __restrict__ out_X,
    float* __restrict__ out_perms, float* __restrict__ out_dist) {
  int b = blockIdx.x, lane = threadIdx.x;
  __shared__ double P[2500];
  __shared__ double cost[2500];
  __shared__ double rs[50];
  __shared__ double u[51];
  __shared__ int p[51];
  __shared__ int wayl[51];
  const size_t base = (size_t)b * 2500;

  // ---- Sinkhorn ----
  for (int e = lane; e < 2500; e += 64) {
    double m = 0.0;
#pragma unroll
    for (int pz = 0; pz < NPART; ++pz)
      m += (double)Mpart[(size_t)pz * PSIZE + base + e];
    m += (double)b2[e % 50];
    m = m >= 0.0 ? m : 0.01 * m;      // leaky_relu in fp64
    P[e] = exp(m);                    // TAU = 1.0
  }
  __syncthreads();
  for (int it = 0; it < 5; ++it) {
    if (lane < 50) { double s = 0; for (int j = 0; j < 50; ++j) s += P[lane * 50 + j]; rs[lane] = s; }
    __syncthreads();
    for (int e = lane; e < 2500; e += 64) P[e] /= rs[e / 50];   // axis=2
    __syncthreads();
    if (lane < 50) { double s = 0; for (int r = 0; r < 50; ++r) s += P[r * 50 + lane]; rs[lane] = s; }
    __syncthreads();
    for (int e = lane; e < 2500; e += 64) P[e] /= rs[e % 50];   // axis=1
    __syncthreads();
  }
  for (int e = lane; e < 2500; e += 64) {
    float f = (float)P[e];
    out_psi[base + e] = f;
    out_X[base + e] = f;              // ALPHA=1.0 => X == psi exactly
    cost[e] = -P[e];
  }
  if (lane < 51) { u[lane] = 0.0; p[lane] = 0; }
  __syncthreads();

  // ---- Hungarian ----
  double v = 0.0;                      // v[lane+1], lane-local (round-7 proven)
  bool lactive = lane < NMAT;
  for (int i = 1; i <= NMAT; ++i) {
    // uniform register caches (all lanes execute these reads; no divergence)
    int pc = (lane <= 50) ? p[lane] : 0;           // p[j] on lane j
    double uc = (lane < 50) ? u[lane + 1] : 0.0;   // u[row] on lane row-1
    bool used = false;
    int way = 0;
    int j0 = 0, j1 = 0;
    double uacc = 0.0, total = 0.0;
    for (int guard = 0; guard < 64; ++guard) {   // defensive cap (normally <=51)
      if (lane == j0 - 1) used = true;           // used[j0] = True (j0>=1)
      int j0u = __builtin_amdgcn_readfirstlane(j0);
      int i0 = (j0u == 0) ? i : __builtin_amdgcn_readlane(pc, j0u);
      double ui0 = readlane_f64(uc, i0 - 1);     // invariant (b): loop-start u
      double cand = HINF;
      if (lactive && !used) {
        cand = cost[(i0 - 1) * NMAT + lane] - ui0 - v;  // v fresh only for free (c)
        way = j0;                                // dead-minv replica
      }
      double m = wave_min_f64(cand);
      unsigned long long bal = __ballot(cand == m);
      j1 = (int)__builtin_ctzll(bal) + 1;        // np.argmin tie-break: lowest j
      if (used) { v -= m; uacc += m; }           // v[used]-=d; defer u[p[used]]+=d
      total += m;                                // row i accumulates ALL deltas
      j0 = j1;
      int j1u = __builtin_amdgcn_readfirstlane(j0);
      if (__builtin_amdgcn_readlane(pc, j1u) == 0) break;   // p static in-loop (a)
    }
    // deferred u-scatter: same targets/values as round-7's per-step updates
    if (used && lactive) u[p[lane + 1]] += uacc; // distinct rows (p injective)
    if (lane == 63) u[i] += total;               // virtual col 0: p[0]=i
    if (lactive) wayl[lane + 1] = way;
    __syncthreads();
    if (lane == 0) {                   // augment (serial; path <= 50, bounded)
      int j = j1;
      for (int step = 0; step < 64 && j != 0; ++step) {
        int jw = wayl[j];
        p[j] = (jw == 0) ? i : p[jw];
        j = jw;
      }
    }
    __syncthreads();
  }

  // perms one-hot + dist (fp32 outputs)
  size_t pbase = (size_t)b * 2500;
  for (int e = lane; e < 2500; e += 64) out_perms[pbase + e] = 0.0f;
  __syncthreads();
  double val = 0.0;
  if (lactive) {
    int row = p[lane + 1] - 1;
    if (row < 0) row = 0;              // defensive clamp (provably unreachable)
    if (row > 49) row = 49;
    out_perms[pbase + (size_t)row * NMAT + lane] = 1.0f;
    val = P[(size_t)row * NMAT + lane];
  }
#pragma unroll
  for (int s = 32; s > 0; s >>= 1) val += __shfl_xor(val, s, 64);
  if (lane == 0) out_dist[b] = (float)(val / (double)NMAT);
}

// ---------------------------------------------------------------------------
extern "C" void kernel_launch(void* const* d_in, const int* in_sizes, int n_in,
                              void* d_out, int out_size, void* d_ws, size_t ws_size,
                              hipStream_t stream) {
  const float* x  = (const float*)d_in[0];   // fp32 per the reference dtypes
  const float* W1 = (const float*)d_in[1];
  const float* b1 = (const float*)d_in[2];
  const float* W2 = (const float*)d_in[3];
  const float* b2 = (const float*)d_in[4];
  float* out = (float*)d_out;                // outputs float32 (round-8/11 finding)
  float* out_psi   = out;
  float* out_perms = out + PSIZE;
  float* out_X     = out + 2 * PSIZE;
  float* out_dist  = out + 3 * PSIZE;

  if (ws_size < (size_t)WS_MIN) return;

  char* ws = (char*)d_ws;
  float* Mpart = (float*)(ws + WS_M_OFF);
  u16* Xh  = (u16*)(ws + WS_XH_OFF);
  u16* Xl  = (u16*)(ws + WS_XL_OFF);
  u16* W1h = (u16*)(ws + WS_W1H_OFF);
  u16* W1l = (u16*)(ws + WS_W1L_OFF);
  u16* W2h = (u16*)(ws + WS_W2H_OFF);
  u16* W2l = (u16*)(ws + WS_W2L_OFF);
  u32* hbuf = (u32*)(ws + WS_H_OFF);
  long long avail = (long long)ws_size - WS_H_OFF;
  int max_rows = (int)(avail / (HDIM * 4));
  max_rows = (max_rows / 128) * 128;
  if (max_rows > ROWS) max_rows = ROWS;

  // one-time conversions: split-bf16 pack (X, W1) + split-bf16 W2^T planes
  hipLaunchKernelGGL(convert_x, dim3(1600), dim3(256), 0, stream, x, Xh, Xl);
  hipLaunchKernelGGL(convert_w1, dim3(1024), dim3(256), 0, stream, W1, W1h, W1l);
  hipLaunchKernelGGL(convert_w2, dim3(1024), dim3(256), 0, stream, W2, W2h, W2l);

  for (int r0 = 0; r0 < ROWS; r0 += max_rows) {
    int rows = (ROWS - r0 < max_rows) ? (ROWS - r0) : max_rows;
    hipLaunchKernelGGL(gemm1_mfma, dim3((rows / 128) * 32), dim3(256), 0, stream,
                       Xh, Xl, W1h, W1l, b1, hbuf, r0 / 128, rows);
    hipLaunchKernelGGL(gemm2_bf16, dim3(rows / 16, NPART), dim3(64), 0, stream,
                       hbuf, W2h, W2l, Mpart, r0, rows);
  }
  hipLaunchKernelGGL(sinkhorn_hungarian, dim3(BATCH), dim3(64), 0, stream,
                     Mpart, b2, out_psi, out_X, out_perms, out_dist);
}